// Round 12
// baseline (185.150 us; speedup 1.0000x reference)
//
#include <hip/hip_runtime.h>
#include <float.h>
#include <math.h>

// B=65536 rows, C=1000 cols, fp32. One wave per row, 8 contiguous rows/wave
// (R10 mapping, 63.3us). R12 attacks the measured issue-saturation
// (~550-600 issue-cyc/row x 4 waves/SIMD ~= 2375 wall-cyc/row/SIMD):
//  (1) DPP wave64 reductions (quad_perm xor1/xor2, half_mirror, mirror,
//      bcast15 rows{1,3}, bcast31 rows{2,3}, readlane63) replace all
//      ds_swizzle butterflies: fewer insts, VALU-latency chains (no DS).
//  (2) y-space math: y = x*log2e once; exps become single v_exp_f32 (exp2),
//      wL pre-scaled by ln2 so L=dot(y,wL*ln2); divisions -> v_rcp_f32.
//      H_hat = ln2*(W'/S - my - log2 S); nll = ln2*(log2 S2 - (yl-my)*rT).
//      Sentinel -FLT_MAX/2 (finite after *log2e; exp2 underflows to 0).
//  (3) final mean fused into the row kernel: last-arriving block (device
//      atomic counter, zeroed per call via 4B hipMemsetAsync) sums the 2048
//      block partials in FIXED order (deterministic) and writes out.

static constexpr int   kC4    = 250;   // float4 per row (1000 floats)
static constexpr int   kBlock = 256;   // 4 waves per block
static constexpr int   kGrid  = 2048;  // 8192 waves
static constexpr int   kWavesTotal = kGrid * (kBlock / 64);
static constexpr int   kRPW   = 8;     // rows per wave (contiguous chunk)
static constexpr float kEps     = 1.1920928955078125e-07f;  // FLT_EPSILON
static constexpr float kInvLogC = 0.14476482730108395f;     // 1/ln(1000)
static constexpr float kLn2     = 0.6931471805599453f;
static constexpr float kLog2e   = 1.4426950408889634f;
static constexpr float kSent    = -1.7014118e38f;  // -FLT_MAX/2 (finite * log2e)

// ---------------- DPP wave64 reductions (rocPRIM sequence) ----------------
template <int Ctrl, int Rmask>
__device__ __forceinline__ float dpp_add(float v) {
  int t = __builtin_amdgcn_update_dpp(0, __builtin_bit_cast(int, v),
                                      Ctrl, Rmask, 0xf, false);
  return v + __builtin_bit_cast(float, t);
}
template <int Ctrl, int Rmask>
__device__ __forceinline__ float dpp_max(float v) {
  int t = __builtin_amdgcn_update_dpp((int)0xFF800000,  // -inf for masked rows
                                      __builtin_bit_cast(int, v),
                                      Ctrl, Rmask, 0xf, false);
  return fmaxf(v, __builtin_bit_cast(float, t));
}
__device__ __forceinline__ float bcast63(float v) {
  return __builtin_bit_cast(
      float, __builtin_amdgcn_readlane(__builtin_bit_cast(int, v), 63));
}
__device__ __forceinline__ float wred_sum_dpp(float v) {
  v = dpp_add<0xB1, 0xF>(v);   // quad_perm [1,0,3,2]  (xor 1)
  v = dpp_add<0x4E, 0xF>(v);   // quad_perm [2,3,0,1]  (xor 2)
  v = dpp_add<0x141, 0xF>(v);  // row_half_mirror
  v = dpp_add<0x140, 0xF>(v);  // row_mirror
  v = dpp_add<0x142, 0xA>(v);  // row_bcast15 -> rows 1,3
  v = dpp_add<0x143, 0xC>(v);  // row_bcast31 -> rows 2,3
  return bcast63(v);
}
__device__ __forceinline__ float wred_max_dpp(float v) {
  v = dpp_max<0xB1, 0xF>(v);
  v = dpp_max<0x4E, 0xF>(v);
  v = dpp_max<0x141, 0xF>(v);
  v = dpp_max<0x140, 0xF>(v);
  v = dpp_max<0x142, 0xA>(v);
  v = dpp_max<0x143, 0xC>(v);
  return bcast63(v);
}
__device__ __forceinline__ void wred_sum3_dpp(float& a, float& b, float& c) {
  a = dpp_add<0xB1, 0xF>(a);  b = dpp_add<0xB1, 0xF>(b);  c = dpp_add<0xB1, 0xF>(c);
  a = dpp_add<0x4E, 0xF>(a);  b = dpp_add<0x4E, 0xF>(b);  c = dpp_add<0x4E, 0xF>(c);
  a = dpp_add<0x141, 0xF>(a); b = dpp_add<0x141, 0xF>(b); c = dpp_add<0x141, 0xF>(c);
  a = dpp_add<0x140, 0xF>(a); b = dpp_add<0x140, 0xF>(b); c = dpp_add<0x140, 0xF>(c);
  a = dpp_add<0x142, 0xA>(a); b = dpp_add<0x142, 0xA>(b); c = dpp_add<0x142, 0xA>(c);
  a = dpp_add<0x143, 0xC>(a); b = dpp_add<0x143, 0xC>(b); c = dpp_add<0x143, 0xC>(c);
  a = bcast63(a); b = bcast63(b); c = bcast63(c);
}

// ---------------- per-pass helpers (y-space) ------------------------------
__device__ __forceinline__ void scale4(float4& c) {
  c.x *= kLog2e; c.y *= kLog2e; c.z *= kLog2e; c.w *= kLog2e;
}
__device__ __forceinline__ void p1_dot_max(const float4 y, const float4 w,
                                           float& L, float& m) {
  L = fmaf(y.x, w.x, L); L = fmaf(y.y, w.y, L);
  L = fmaf(y.z, w.z, L); L = fmaf(y.w, w.w, L);
  m = fmaxf(m, fmaxf(fmaxf(y.x, y.y), fmaxf(y.z, y.w)));
}
__device__ __forceinline__ void p2_sumexp(const float4 y, const float my,
                                          float& S, float& Wp) {
  float e;
  e = __builtin_amdgcn_exp2f(y.x - my); S += e; Wp = fmaf(e, y.x, Wp);
  e = __builtin_amdgcn_exp2f(y.y - my); S += e; Wp = fmaf(e, y.y, Wp);
  e = __builtin_amdgcn_exp2f(y.z - my); S += e; Wp = fmaf(e, y.z, Wp);
  e = __builtin_amdgcn_exp2f(y.w - my); S += e; Wp = fmaf(e, y.w, Wp);
}
__device__ __forceinline__ void p3_sumexp2(const float4 y, const float rT,
                                           const float nmy, float& S2) {
  S2 += __builtin_amdgcn_exp2f(fmaf(y.x, rT, nmy));
  S2 += __builtin_amdgcn_exp2f(fmaf(y.y, rT, nmy));
  S2 += __builtin_amdgcn_exp2f(fmaf(y.z, rT, nmy));
  S2 += __builtin_amdgcn_exp2f(fmaf(y.w, rT, nmy));
}
__device__ __forceinline__ float pick_lab(const float4 v, const int el) {
  return (el == 0) ? v.x : (el == 1) ? v.y : (el == 2) ? v.z : v.w;
}

#define SENT4 make_float4(kSent, kSent, kSent, kSent)

// ---- main kernel: B == 65536, 8 contiguous rows/wave, fused final mean ----
__global__ __launch_bounds__(kBlock) void ats_row_kernel_c8(
    const float* __restrict__ X, const int* __restrict__ labels,
    const float* __restrict__ wL, const float* __restrict__ wH,
    const float* __restrict__ bb, double* __restrict__ partial,
    unsigned* __restrict__ counter, float* __restrict__ out, int B) {
  const int lane   = threadIdx.x & 63;
  const int wib    = threadIdx.x >> 6;
  const int wid    = blockIdx.x * (kBlock / 64) + wib;
  const bool tailok = lane < (kC4 - 192);

  // wL pre-scaled by ln2 (so L = dot(y, wL*ln2) = dot(x, wL)), cached in regs
  const float4* WLr = reinterpret_cast<const float4*>(wL);
  float4 w0 = WLr[lane];
  float4 w1 = WLr[64 + lane];
  float4 w2 = WLr[128 + lane];
  float4 w3 = tailok ? WLr[192 + lane] : make_float4(0.f, 0.f, 0.f, 0.f);
  w0.x *= kLn2; w0.y *= kLn2; w0.z *= kLn2; w0.w *= kLn2;
  w1.x *= kLn2; w1.y *= kLn2; w1.z *= kLn2; w1.w *= kLn2;
  w2.x *= kLn2; w2.y *= kLn2; w2.z *= kLn2; w2.w *= kLn2;
  w3.x *= kLn2; w3.y *= kLn2; w3.z *= kLn2; w3.w *= kLn2;
  const float wH0 = wH[0];
  const float b0  = bb[0];

  double acc = 0.0;
  const int base = wid * kRPW;

  float4 c0, c1, c2, c3;
  int labc;
  {
    const float4* Xr = reinterpret_cast<const float4*>(X) + (size_t)base * kC4;
    c0 = Xr[lane]; c1 = Xr[64 + lane]; c2 = Xr[128 + lane];
    c3 = tailok ? Xr[192 + lane] : SENT4;
    labc = labels[base];
  }

  for (int i = 0; i < kRPW; ++i) {
    // ---- prefetch next (adjacent) row — conditional, R3/R10 style
    float4 n0 = SENT4, n1 = SENT4, n2 = SENT4, n3 = SENT4;
    int labn = 0;
    if (i + 1 < kRPW) {
      const float4* Xn =
          reinterpret_cast<const float4*>(X) + (size_t)(base + i + 1) * kC4;
      n0 = Xn[lane]; n1 = Xn[64 + lane]; n2 = Xn[128 + lane];
      n3 = tailok ? Xn[192 + lane] : SENT4;
      labn = labels[base + i + 1];
    }

    // ---- to y-space: y = x * log2e (sentinel stays finite)
    scale4(c0); scale4(c1); scale4(c2); scale4(c3);

    // ---- pass1: per-lane max + dot, DPP max reduce
    float L = 0.f, my = -FLT_MAX;
    p1_dot_max(c0, w0, L, my); p1_dot_max(c1, w1, L, my);
    p1_dot_max(c2, w2, L, my); p1_dot_max(c3, w3, L, my);
    my = wred_max_dpp(my);

    // ---- pass2: S = sum exp2(y-my), W' = sum exp2(y-my)*y
    float S = 0.f, Wp = 0.f;
    p2_sumexp(c0, my, S, Wp); p2_sumexp(c1, my, S, Wp);
    p2_sumexp(c2, my, S, Wp); p2_sumexp(c3, my, S, Wp);
    wred_sum3_dpp(S, Wp, L);

    // ---- y[label]: wave-uniform slot/elem, one bpermute broadcast
    const int c4l = labc >> 2;
    const int sl  = c4l >> 6, ln = c4l & 63, el = labc & 3;
    float4 v = (sl == 0) ? c0 : (sl == 1) ? c1 : (sl == 2) ? c2 : c3;
    const float yl = __shfl(pick_lab(v, el), ln, 64);

    // ---- temperature: Hhat = ln2*(W'/S - my - log2 S)
    const float rcpS = __builtin_amdgcn_rcpf(S);
    const float Hhat = kLn2 * (Wp * rcpS - my - __builtin_amdgcn_logf(S));
    const float a    = L + fmaf(wH0, Hhat * kInvLogC, b0);
    const float sp   = (a > 0.f) ? (a + log1pf(__expf(-a))) : log1pf(__expf(a));
    const float T    = fmaxf(sp, kEps);
    const float rT   = __builtin_amdgcn_rcpf(T);
    const float nmy  = -my * rT;

    // ---- pass3: S2 = sum exp2((y-my)*rT)
    float S2 = 0.f;
    p3_sumexp2(c0, rT, nmy, S2); p3_sumexp2(c1, rT, nmy, S2);
    p3_sumexp2(c2, rT, nmy, S2); p3_sumexp2(c3, rT, nmy, S2);
    S2 = wred_sum_dpp(S2);

    // nll = ln2 * (log2(S2) - (yl - my)*rT)
    const float nll = kLn2 * (__builtin_amdgcn_logf(S2) - fmaf(yl, rT, nmy));
    acc += (double)nll;

    // ---- rotate pipeline (raw next row)
    c0 = n0; c1 = n1; c2 = n2; c3 = n3; labc = labn;
  }

  // ---- block partial, then last-arriving block does the (fixed-order) mean
  __shared__ double sacc[kBlock / 64];
  __shared__ unsigned slast;
  if (lane == 0) sacc[wib] = acc;
  __syncthreads();
  if (threadIdx.x == 0) {
    const double p = (sacc[0] + sacc[1]) + (sacc[2] + sacc[3]);
    __hip_atomic_store(&partial[blockIdx.x], p, __ATOMIC_RELEASE,
                       __HIP_MEMORY_SCOPE_AGENT);
    const unsigned prev = __hip_atomic_fetch_add(
        counter, 1u, __ATOMIC_ACQ_REL, __HIP_MEMORY_SCOPE_AGENT);
    slast = (prev == (unsigned)(gridDim.x - 1)) ? 1u : 0u;
  }
  __syncthreads();
  if (slast) {  // block-uniform branch
    double a = 0.0;
    for (int i = threadIdx.x; i < kGrid; i += kBlock)
      a += __hip_atomic_load(&partial[i], __ATOMIC_RELAXED,
                             __HIP_MEMORY_SCOPE_AGENT);
    __shared__ double sred[kBlock];
    sred[threadIdx.x] = a;
    __syncthreads();
#pragma unroll
    for (int s = kBlock / 2; s > 0; s >>= 1) {
      if ((int)threadIdx.x < s) sred[threadIdx.x] += sred[threadIdx.x + s];
      __syncthreads();
    }
    if (threadIdx.x == 0) out[0] = (float)(sred[0] / (double)B);
  }
}

// ---- generic fallback (any B): R10 gen kernel + separate final ----------
__device__ __forceinline__ float wred_sum_shfl(float v) {
#pragma unroll
  for (int off = 32; off > 0; off >>= 1) v += __shfl_xor(v, off, 64);
  return v;
}
__device__ __forceinline__ float wred_max_shfl(float v) {
#pragma unroll
  for (int off = 32; off > 0; off >>= 1) v = fmaxf(v, __shfl_xor(v, off, 64));
  return v;
}
__global__ __launch_bounds__(kBlock) void ats_row_kernel_gen(
    const float* __restrict__ X, const int* __restrict__ labels,
    const float* __restrict__ wL, const float* __restrict__ wH,
    const float* __restrict__ bb, double* __restrict__ partial, int B) {
  const int lane   = threadIdx.x & 63;
  const int wib    = threadIdx.x >> 6;
  const int wid    = blockIdx.x * (kBlock / 64) + wib;
  const bool tailok = lane < (kC4 - 192);

  const float4* WLr = reinterpret_cast<const float4*>(wL);
  const float4 w0 = WLr[lane];
  const float4 w1 = WLr[64 + lane];
  const float4 w2 = WLr[128 + lane];
  const float4 w3 = tailok ? WLr[192 + lane] : make_float4(0.f, 0.f, 0.f, 0.f);
  const float wH0 = wH[0];
  const float b0  = bb[0];

  double acc = 0.0;
  for (int row = wid; row < B; row += kWavesTotal) {
    const float4* Xr = reinterpret_cast<const float4*>(X) + (size_t)row * kC4;
    float4 c0 = Xr[lane], c1 = Xr[64 + lane], c2 = Xr[128 + lane];
    float4 c3 = tailok ? Xr[192 + lane] : SENT4;
    const int labc = labels[row];

    float L = 0.f, m = -FLT_MAX;
    float S = 0.f, W = 0.f;
    {  // natural-space math (simple, correctness-first fallback)
      float e;
      L = fmaf(c0.x, w0.x, L); L = fmaf(c0.y, w0.y, L);
      L = fmaf(c0.z, w0.z, L); L = fmaf(c0.w, w0.w, L);
      m = fmaxf(m, fmaxf(fmaxf(c0.x, c0.y), fmaxf(c0.z, c0.w)));
      L = fmaf(c1.x, w1.x, L); L = fmaf(c1.y, w1.y, L);
      L = fmaf(c1.z, w1.z, L); L = fmaf(c1.w, w1.w, L);
      m = fmaxf(m, fmaxf(fmaxf(c1.x, c1.y), fmaxf(c1.z, c1.w)));
      L = fmaf(c2.x, w2.x, L); L = fmaf(c2.y, w2.y, L);
      L = fmaf(c2.z, w2.z, L); L = fmaf(c2.w, w2.w, L);
      m = fmaxf(m, fmaxf(fmaxf(c2.x, c2.y), fmaxf(c2.z, c2.w)));
      L = fmaf(c3.x, w3.x, L); L = fmaf(c3.y, w3.y, L);
      L = fmaf(c3.z, w3.z, L); L = fmaf(c3.w, w3.w, L);
      m = fmaxf(m, fmaxf(fmaxf(c3.x, c3.y), fmaxf(c3.z, c3.w)));
      m = wred_max_shfl(m);
      e = __expf(c0.x - m); S += e; W = fmaf(e, c0.x, W);
      e = __expf(c0.y - m); S += e; W = fmaf(e, c0.y, W);
      e = __expf(c0.z - m); S += e; W = fmaf(e, c0.z, W);
      e = __expf(c0.w - m); S += e; W = fmaf(e, c0.w, W);
      e = __expf(c1.x - m); S += e; W = fmaf(e, c1.x, W);
      e = __expf(c1.y - m); S += e; W = fmaf(e, c1.y, W);
      e = __expf(c1.z - m); S += e; W = fmaf(e, c1.z, W);
      e = __expf(c1.w - m); S += e; W = fmaf(e, c1.w, W);
      e = __expf(c2.x - m); S += e; W = fmaf(e, c2.x, W);
      e = __expf(c2.y - m); S += e; W = fmaf(e, c2.y, W);
      e = __expf(c2.z - m); S += e; W = fmaf(e, c2.z, W);
      e = __expf(c2.w - m); S += e; W = fmaf(e, c2.w, W);
      e = __expf(c3.x - m); S += e; W = fmaf(e, c3.x, W);
      e = __expf(c3.y - m); S += e; W = fmaf(e, c3.y, W);
      e = __expf(c3.z - m); S += e; W = fmaf(e, c3.z, W);
      e = __expf(c3.w - m); S += e; W = fmaf(e, c3.w, W);
      S = wred_sum_shfl(S); W = wred_sum_shfl(W); L = wred_sum_shfl(L);
    }
    const int c4l = labc >> 2;
    const int sl = c4l >> 6, ln = c4l & 63, el = labc & 3;
    float4 v = (sl == 0) ? c0 : (sl == 1) ? c1 : (sl == 2) ? c2 : c3;
    const float xl = __shfl(pick_lab(v, el), ln, 64);
    const float Hhat = W / S - m - __logf(S);
    const float a = L + wH0 * (Hhat * kInvLogC) + b0;
    const float sp = (a > 0.f) ? (a + log1pf(__expf(-a))) : log1pf(__expf(a));
    const float T = fmaxf(sp, kEps);
    const float rT = 1.0f / T, nmrT = -m * rT;
    float S2 = 0.f;
    S2 += __expf(fmaf(c0.x, rT, nmrT)); S2 += __expf(fmaf(c0.y, rT, nmrT));
    S2 += __expf(fmaf(c0.z, rT, nmrT)); S2 += __expf(fmaf(c0.w, rT, nmrT));
    S2 += __expf(fmaf(c1.x, rT, nmrT)); S2 += __expf(fmaf(c1.y, rT, nmrT));
    S2 += __expf(fmaf(c1.z, rT, nmrT)); S2 += __expf(fmaf(c1.w, rT, nmrT));
    S2 += __expf(fmaf(c2.x, rT, nmrT)); S2 += __expf(fmaf(c2.y, rT, nmrT));
    S2 += __expf(fmaf(c2.z, rT, nmrT)); S2 += __expf(fmaf(c2.w, rT, nmrT));
    S2 += __expf(fmaf(c3.x, rT, nmrT)); S2 += __expf(fmaf(c3.y, rT, nmrT));
    S2 += __expf(fmaf(c3.z, rT, nmrT)); S2 += __expf(fmaf(c3.w, rT, nmrT));
    S2 = wred_sum_shfl(S2);
    acc += (double)(__logf(S2) - fmaf(xl, rT, nmrT));
  }
  __shared__ double sacc[kBlock / 64];
  if (lane == 0) sacc[wib] = acc;
  __syncthreads();
  if (threadIdx.x == 0)
    partial[blockIdx.x] = (sacc[0] + sacc[1]) + (sacc[2] + sacc[3]);
}

__global__ __launch_bounds__(256) void ats_final_kernel(
    const double* __restrict__ partial, float* __restrict__ out, int n, int B) {
  __shared__ double sdata[256];
  double a = 0.0;
  for (int i = threadIdx.x; i < n; i += 256) a += partial[i];
  sdata[threadIdx.x] = a;
  __syncthreads();
#pragma unroll
  for (int s = 128; s > 0; s >>= 1) {
    if ((int)threadIdx.x < s) sdata[threadIdx.x] += sdata[threadIdx.x + s];
    __syncthreads();
  }
  if (threadIdx.x == 0) out[0] = (float)(sdata[0] / (double)B);
}

extern "C" void kernel_launch(void* const* d_in, const int* in_sizes, int n_in,
                              void* d_out, int out_size, void* d_ws, size_t ws_size,
                              hipStream_t stream) {
  (void)n_in; (void)out_size; (void)ws_size;
  const float* X   = (const float*)d_in[0];
  const int*   lab = (const int*)d_in[1];
  const float* wL  = (const float*)d_in[2];
  const float* wH  = (const float*)d_in[3];
  const float* bb  = (const float*)d_in[4];
  const int B = in_sizes[1];  // 65536 labels
  unsigned* counter = (unsigned*)d_ws;                      // [0,4)
  double*   partial = (double*)((char*)d_ws + 256);         // kGrid doubles
  float*    out     = (float*)d_out;

  if (B == kWavesTotal * kRPW) {
    hipMemsetAsync(d_ws, 0, 4, stream);  // zero the arrival counter per call
    ats_row_kernel_c8<<<kGrid, kBlock, 0, stream>>>(X, lab, wL, wH, bb,
                                                    partial, counter, out, B);
  } else {
    ats_row_kernel_gen<<<kGrid, kBlock, 0, stream>>>(X, lab, wL, wH, bb,
                                                     partial, B);
    ats_final_kernel<<<1, 256, 0, stream>>>(partial, out, kGrid, B);
  }
}

// Round 13
// 62.302 us; speedup vs baseline: 2.9718x; 2.9718x over previous
//
#include <hip/hip_runtime.h>
#include <float.h>
#include <math.h>

// B=65536 rows, C=1000 cols, fp32. One wave per row, 8 contiguous rows/wave
// (R10 mapping, 63.3us best). R13 = R10 + PREFETCH DEPTH 2:
// R12's rocprof finally showed the row kernel: VALUBusy ~17% -> NOT VALU-bound.
// R10 model: each wave holds only 13KB in flight, cycles ~9500cyc/row
// (Little's law: delivered 15 GB/s/CU vs 24.6 available). Depth-2 prefetch
// doubles outstanding bytes/wave with single-row compute (R11's pair-compute
// ballooned VGPR; this keeps temps small). Fully-unrolled loop, 3 rotating
// row buffers, __launch_bounds__(256,4) pins <=128 VGPR (4 waves/SIMD).
// Math per row (R3/R10-verbatim): pass1 m,L; pass2 S,W; T; pass3 S2; nll.
// Mean: per-block double partial -> separate tiny final kernel.

static constexpr int   kC4    = 250;   // float4 per row (1000 floats)
static constexpr int   kBlock = 256;   // 4 waves per block
static constexpr int   kGrid  = 2048;  // 8192 waves
static constexpr int   kWavesTotal = kGrid * (kBlock / 64);
static constexpr int   kRPW   = 8;     // rows per wave (contiguous chunk)
static constexpr float kEps   = 1.1920928955078125e-07f;  // FLT_EPSILON
static constexpr float kLogC  = 6.907755279f;             // ln(1000)

__device__ __forceinline__ float wred_max(float v) {
#pragma unroll
  for (int off = 32; off > 0; off >>= 1) v = fmaxf(v, __shfl_xor(v, off, 64));
  return v;
}
__device__ __forceinline__ float wred_sum(float v) {
#pragma unroll
  for (int off = 32; off > 0; off >>= 1) v += __shfl_xor(v, off, 64);
  return v;
}

__device__ __forceinline__ void p1_dot_max(const float4 c, const float4 w,
                                           float& L, float& m) {
  L = fmaf(c.x, w.x, L); L = fmaf(c.y, w.y, L);
  L = fmaf(c.z, w.z, L); L = fmaf(c.w, w.w, L);
  m = fmaxf(m, fmaxf(fmaxf(c.x, c.y), fmaxf(c.z, c.w)));
}
__device__ __forceinline__ void p2_sumexp(const float4 c, const float m,
                                          float& S, float& W) {
  float e;
  e = __expf(c.x - m); S += e; W = fmaf(e, c.x, W);
  e = __expf(c.y - m); S += e; W = fmaf(e, c.y, W);
  e = __expf(c.z - m); S += e; W = fmaf(e, c.z, W);
  e = __expf(c.w - m); S += e; W = fmaf(e, c.w, W);
}
__device__ __forceinline__ void p3_sumexp2(const float4 c, const float rT,
                                           const float nmrT, float& S2) {
  S2 += __expf(fmaf(c.x, rT, nmrT)); S2 += __expf(fmaf(c.y, rT, nmrT));
  S2 += __expf(fmaf(c.z, rT, nmrT)); S2 += __expf(fmaf(c.w, rT, nmrT));
}
__device__ __forceinline__ float pick_lab(const float4 v, const int el) {
  return (el == 0) ? v.x : (el == 1) ? v.y : (el == 2) ? v.z : v.w;
}

#define SENT4 make_float4(-FLT_MAX, -FLT_MAX, -FLT_MAX, -FLT_MAX)

// ---- shared per-row body (R10-verbatim) ----------------------------------
__device__ __forceinline__ float row_nll(
    const float4 c0, const float4 c1, const float4 c2, const float4 c3,
    const float4 w0, const float4 w1, const float4 w2, const float4 w3,
    const int labc, const float wH0, const float b0) {
  float L = 0.f, m = -FLT_MAX;
  p1_dot_max(c0, w0, L, m); p1_dot_max(c1, w1, L, m);
  p1_dot_max(c2, w2, L, m); p1_dot_max(c3, w3, L, m);
  m = wred_max(m);

  float S = 0.f, W = 0.f;
  p2_sumexp(c0, m, S, W); p2_sumexp(c1, m, S, W);
  p2_sumexp(c2, m, S, W); p2_sumexp(c3, m, S, W);
  S = wred_sum(S);
  W = wred_sum(W);
  L = wred_sum(L);

  const int c4l = labc >> 2;
  const int sl  = c4l >> 6, ln = c4l & 63, el = labc & 3;
  float4 v = (sl == 0) ? c0 : (sl == 1) ? c1 : (sl == 2) ? c2 : c3;
  const float xl = __shfl(pick_lab(v, el), ln, 64);

  const float Hhat = W / S - m - __logf(S);
  const float a    = L + wH0 * (Hhat / kLogC) + b0;
  const float sp   = (a > 0.f) ? (a + log1pf(__expf(-a))) : log1pf(__expf(a));
  const float T    = fmaxf(sp, kEps);
  const float rT   = 1.0f / T;
  const float nmrT = -m * rT;

  float S2 = 0.f;
  p3_sumexp2(c0, rT, nmrT, S2); p3_sumexp2(c1, rT, nmrT, S2);
  p3_sumexp2(c2, rT, nmrT, S2); p3_sumexp2(c3, rT, nmrT, S2);
  S2 = wred_sum(S2);

  return __logf(S2) - fmaf(xl, rT, nmrT);  // logS2 - (xl-m)/T
}

// ---- specialized: B == kWavesTotal*kRPW, contiguous chunks, DEPTH-2 ------
__global__ __launch_bounds__(kBlock, 4) void ats_row_kernel_d2(
    const float* __restrict__ X, const int* __restrict__ labels,
    const float* __restrict__ wL, const float* __restrict__ wH,
    const float* __restrict__ bb, double* __restrict__ partial) {
  const int lane   = threadIdx.x & 63;
  const int wib    = threadIdx.x >> 6;
  const int wid    = blockIdx.x * (kBlock / 64) + wib;
  const bool tailok = lane < (kC4 - 192);

  const float4* WLr = reinterpret_cast<const float4*>(wL);
  const float4 w0 = WLr[lane];
  const float4 w1 = WLr[64 + lane];
  const float4 w2 = WLr[128 + lane];
  const float4 w3 = tailok ? WLr[192 + lane] : make_float4(0.f, 0.f, 0.f, 0.f);
  const float wH0 = wH[0];
  const float b0  = bb[0];

  double acc = 0.0;
  const int base = wid * kRPW;

  // prologue: rows base+0 (A) and base+1 (B) in flight
  float4 a0, a1, a2, a3, b0_, b1_, b2_, b3_;
  int labA, labB;
  {
    const float4* Xa = reinterpret_cast<const float4*>(X) + (size_t)base * kC4;
    a0 = Xa[lane]; a1 = Xa[64 + lane]; a2 = Xa[128 + lane];
    a3 = tailok ? Xa[192 + lane] : SENT4;
    labA = labels[base];
    const float4* Xb = Xa + kC4;
    b0_ = Xb[lane]; b1_ = Xb[64 + lane]; b2_ = Xb[128 + lane];
    b3_ = tailok ? Xb[192 + lane] : SENT4;
    labB = labels[base + 1];
  }

#pragma unroll
  for (int i = 0; i < kRPW; ++i) {
    // issue prefetch of row i+2 (compile-time condition after full unroll)
    float4 n0 = SENT4, n1 = SENT4, n2 = SENT4, n3 = SENT4;
    int labN = 0;
    if (i + 2 < kRPW) {
      const float4* Xn =
          reinterpret_cast<const float4*>(X) + (size_t)(base + i + 2) * kC4;
      n0 = Xn[lane]; n1 = Xn[64 + lane]; n2 = Xn[128 + lane];
      n3 = tailok ? Xn[192 + lane] : SENT4;
      labN = labels[base + i + 2];
    }

    acc += (double)row_nll(a0, a1, a2, a3, w0, w1, w2, w3, labA, wH0, b0);

    // rotate: full unroll renames registers (no v_mov chains)
    a0 = b0_; a1 = b1_; a2 = b2_; a3 = b3_; labA = labB;
    b0_ = n0; b1_ = n1; b2_ = n2; b3_ = n3; labB = labN;
  }

  __shared__ double sacc[kBlock / 64];
  if (lane == 0) sacc[wib] = acc;
  __syncthreads();
  if (threadIdx.x == 0)
    partial[blockIdx.x] = (sacc[0] + sacc[1]) + (sacc[2] + sacc[3]);
}

// ---- generic fallback: R3 mapping, depth-1 (any B) -----------------------
__global__ __launch_bounds__(kBlock) void ats_row_kernel_gen(
    const float* __restrict__ X, const int* __restrict__ labels,
    const float* __restrict__ wL, const float* __restrict__ wH,
    const float* __restrict__ bb, double* __restrict__ partial, int B) {
  const int lane   = threadIdx.x & 63;
  const int wib    = threadIdx.x >> 6;
  const int wid    = blockIdx.x * (kBlock / 64) + wib;
  const bool tailok = lane < (kC4 - 192);

  const float4* WLr = reinterpret_cast<const float4*>(wL);
  const float4 w0 = WLr[lane];
  const float4 w1 = WLr[64 + lane];
  const float4 w2 = WLr[128 + lane];
  const float4 w3 = tailok ? WLr[192 + lane] : make_float4(0.f, 0.f, 0.f, 0.f);
  const float wH0 = wH[0];
  const float b0  = bb[0];

  double acc = 0.0;
  int row = wid;
  float4 c0, c1, c2, c3;
  int labc = 0;
  if (row < B) {
    const float4* Xr = reinterpret_cast<const float4*>(X) + (size_t)row * kC4;
    c0 = Xr[lane]; c1 = Xr[64 + lane]; c2 = Xr[128 + lane];
    c3 = tailok ? Xr[192 + lane] : SENT4;
    labc = labels[row];
  }
  for (; row < B; row += kWavesTotal) {
    const int nrow = row + kWavesTotal;
    float4 n0 = SENT4, n1 = SENT4, n2 = SENT4, n3 = SENT4;
    int labn = 0;
    if (nrow < B) {
      const float4* Xn = reinterpret_cast<const float4*>(X) + (size_t)nrow * kC4;
      n0 = Xn[lane]; n1 = Xn[64 + lane]; n2 = Xn[128 + lane];
      n3 = tailok ? Xn[192 + lane] : SENT4;
      labn = labels[nrow];
    }
    acc += (double)row_nll(c0, c1, c2, c3, w0, w1, w2, w3, labc, wH0, b0);
    c0 = n0; c1 = n1; c2 = n2; c3 = n3; labc = labn;
  }
  __shared__ double sacc[kBlock / 64];
  if (lane == 0) sacc[wib] = acc;
  __syncthreads();
  if (threadIdx.x == 0)
    partial[blockIdx.x] = (sacc[0] + sacc[1]) + (sacc[2] + sacc[3]);
}

__global__ __launch_bounds__(256) void ats_final_kernel(
    const double* __restrict__ partial, float* __restrict__ out, int n, int B) {
  __shared__ double sdata[256];
  double a = 0.0;
  for (int i = threadIdx.x; i < n; i += 256) a += partial[i];
  sdata[threadIdx.x] = a;
  __syncthreads();
#pragma unroll
  for (int s = 128; s > 0; s >>= 1) {
    if ((int)threadIdx.x < s) sdata[threadIdx.x] += sdata[threadIdx.x + s];
    __syncthreads();
  }
  if (threadIdx.x == 0) out[0] = (float)(sdata[0] / (double)B);
}

extern "C" void kernel_launch(void* const* d_in, const int* in_sizes, int n_in,
                              void* d_out, int out_size, void* d_ws, size_t ws_size,
                              hipStream_t stream) {
  (void)n_in; (void)out_size; (void)ws_size;
  const float* X   = (const float*)d_in[0];
  const int*   lab = (const int*)d_in[1];
  const float* wL  = (const float*)d_in[2];
  const float* wH  = (const float*)d_in[3];
  const float* bb  = (const float*)d_in[4];
  const int B = in_sizes[1];            // 65536 labels
  double* partial = (double*)d_ws;      // kGrid doubles = 16 KB scratch
  float* out = (float*)d_out;

  if (B == kWavesTotal * kRPW) {
    ats_row_kernel_d2<<<kGrid, kBlock, 0, stream>>>(X, lab, wL, wH, bb, partial);
  } else {
    ats_row_kernel_gen<<<kGrid, kBlock, 0, stream>>>(X, lab, wL, wH, bb,
                                                     partial, B);
  }
  ats_final_kernel<<<1, 256, 0, stream>>>(partial, out, kGrid, B);
}